// Round 22
// baseline (1243.026 us; speedup 1.0000x reference)
//
#include <hip/hip_runtime.h>
#include <hip/hip_bf16.h>

typedef short short8 __attribute__((ext_vector_type(8)));
typedef short s4b __attribute__((ext_vector_type(4)));
typedef float floatx4 __attribute__((ext_vector_type(4)));
typedef unsigned int u32;

#define DEVFN static __device__ __forceinline__

constexpr int L_TOK = 147456;          // 8*96*192
constexpr float ATT_SCALE = 0.17677669529663687f;  // 32^-0.5

DEVFN int win_to_spatial(int t, int sz, int sh, int sw) {
  int w_ = t / 144;
  int n  = t - w_ * 144;
  int nz = w_ >> 8, nh = (w_ >> 4) & 15, nw = w_ & 15;
  int iz = n / 72; int rem = n - iz * 72;
  int ih = rem / 12; int iw = rem - ih * 12;
  int z = nz * 2 + iz + sz;  if (z >= 8)   z -= 8;
  int h = nh * 6 + ih + sh;  if (h >= 96)  h -= 96;
  int wc = nw * 12 + iw + sw; if (wc >= 192) wc -= 192;
  return (z * 96 + h) * 192 + wc;
}

DEVFN void gload16(const void* g, void* l) {
  __builtin_amdgcn_global_load_lds(
      (const __attribute__((address_space(1))) u32*)(g),
      (__attribute__((address_space(3))) u32*)(l), 16, 0, 0);
}

// counted-wait barriers (no vmcnt-0 drain)
DEVFN void bar_vm14() { asm volatile("s_waitcnt vmcnt(14)\n\ts_barrier" ::: "memory"); }
DEVFN void bar_vm12() { asm volatile("s_waitcnt vmcnt(12)\n\ts_barrier" ::: "memory"); }
DEVFN void bar_vm11() { asm volatile("s_waitcnt vmcnt(11)\n\ts_barrier" ::: "memory"); }
DEVFN void bar_vm10() { asm volatile("s_waitcnt vmcnt(10)\n\ts_barrier" ::: "memory"); }
DEVFN void bar_vm8()  { asm volatile("s_waitcnt vmcnt(8)\n\ts_barrier"  ::: "memory"); }
DEVFN void bar_vm7()  { asm volatile("s_waitcnt vmcnt(7)\n\ts_barrier"  ::: "memory"); }
DEVFN void bar_vm6()  { asm volatile("s_waitcnt vmcnt(6)\n\ts_barrier"  ::: "memory"); }
DEVFN void bar_vm0()  { asm volatile("s_waitcnt vmcnt(0)\n\ts_barrier"  ::: "memory"); }
DEVFN void bar_lg()   { asm volatile("s_waitcnt lgkmcnt(0)\n\ts_barrier" ::: "memory"); }

DEVFN float gelu_fast(float x) {
  float e = __expf(-1.702f * x);
  return x * __fdividef(1.0f, 1.0f + e);
}

// ---------------- fused weight convert+transpose (all 4 weights, 1 launch) ---
__global__ __launch_bounds__(256) void convT4_kernel(
    const float* __restrict__ in0, const float* __restrict__ in1,
    const float* __restrict__ in2, const float* __restrict__ in3,
    __hip_bfloat16* __restrict__ o0, __hip_bfloat16* __restrict__ o1,
    __hip_bfloat16* __restrict__ o2, __hip_bfloat16* __restrict__ o3)
{
  int idx = blockIdx.x * 256 + threadIdx.x;   // 0..442367
  const float* in; __hip_bfloat16* out; int K, N;
  if (idx < 110592)      { in = in0; out = o0; K = 192; N = 576; }
  else if (idx < 147456) { in = in1; out = o1; K = 192; N = 192; idx -= 110592; }
  else if (idx < 294912) { in = in2; out = o2; K = 192; N = 768; idx -= 147456; }
  else                   { in = in3; out = o3; K = 768; N = 192; idx -= 294912; }
  int n = idx / K, k = idx - n * K;
  out[idx] = __float2bfloat16(in[(long)k * N + n]);
}

// ---------------- bias expansion, TRANSPOSED: out[t][m][n] -------------------
__global__ __launch_bounds__(256) void biaspre_kernel(
    const float* __restrict__ tab, __hip_bfloat16* __restrict__ out)
{
  int t = blockIdx.x;
  int e0 = blockIdx.y * 2304;
  for (int e = e0 + threadIdx.x; e < e0 + 2304; e += 256) {
    int m = e / 144, n = e - m * 144;
    int izn = n / 72, rn = n - izn * 72, ihn = rn / 12, iwn = rn - ihn * 12;
    int izm = m / 72, rm = m - izm * 72, ihm = rm / 12, iwm = rm - ihm * 12;
    int idx = (izn + 2 * izm) * 828 + (ihn + 6 * ihm) * 23 + (iwn - iwm + 11);
    out[(long)t * 20736 + e] = __float2bfloat16(tab[(long)idx * 384 + t]);
  }
}

// ---------------- fused LN1 + QKV GEMM -> head-major q/k/v (512-thr) ---------
__global__ __launch_bounds__(512) void qkv_kernel(
    const float* __restrict__ x, const float* __restrict__ nw,
    const float* __restrict__ nb,
    const __hip_bfloat16* __restrict__ wqkvT, const float* __restrict__ qbias,
    __hip_bfloat16* __restrict__ oq, __hip_bfloat16* __restrict__ okk,
    __hip_bfloat16* __restrict__ ov, int sz, int sh, int sw)
{
  __shared__ char a_lds[128 * 384];   // LN tile; first 24KB reused as W buf1
  __shared__ char w_lds[64 * 384];    // W buf0
  __shared__ float bias_lds[576];

  int tid = threadIdx.x, lane = tid & 63, wv = tid >> 6;
  int lc = lane & 15, lr = lane >> 4, lr4 = lr * 4;
  long row0 = (long)blockIdx.x * 128;
  const char* Wc = (const char*)wqkvT;

#pragma unroll
  for (int i = 0; i < 3; i++) {
    int ii = i * 8 + wv;
    int p = ii * 1024 + lane * 16;
    int row = p / 384, cb = p - row * 384;
    int sc = (cb >> 4) ^ (row & 7);
    gload16(Wc + (long)row * 384 + sc * 16, w_lds + ii * 1024);
  }
  if (tid < 144) *(float4*)(bias_lds + tid * 4) = *(const float4*)(qbias + tid * 4);

#pragma unroll
  for (int rg = 0; rg < 2; rg++) {
    int row = rg * 64 + (tid >> 3), sub = tid & 7;
    int src = win_to_spatial((int)(row0 + row), sz, sh, sw);
    const float* xp = x + (long)src * 192;
    float4 v[6];
#pragma unroll
    for (int p = 0; p < 3; p++) {
      v[2*p]   = *(const float4*)(xp + p * 64 + sub * 8);
      v[2*p+1] = *(const float4*)(xp + p * 64 + sub * 8 + 4);
    }
    float s = 0.f, sq = 0.f;
#pragma unroll
    for (int i = 0; i < 6; i++) {
      s  += v[i].x + v[i].y + v[i].z + v[i].w;
      sq += v[i].x*v[i].x + v[i].y*v[i].y + v[i].z*v[i].z + v[i].w*v[i].w;
    }
    for (int m = 1; m < 8; m <<= 1) { s += __shfl_xor(s, m); sq += __shfl_xor(sq, m); }
    float mean = s * (1.0f/192.0f);
    float var  = sq * (1.0f/192.0f) - mean * mean;
    float rstd = rsqrtf(var + 1e-5f);
#pragma unroll
    for (int p = 0; p < 3; p++) {
      int ch0 = p * 64 + sub * 8;
      float4 wa = *(const float4*)(nw + ch0), wb_ = *(const float4*)(nw + ch0 + 4);
      float4 ba = *(const float4*)(nb + ch0), bb_ = *(const float4*)(nb + ch0 + 4);
      const float* va = (const float*)&v[2*p];
      const float* wa_p = (const float*)&wa; const float* wb_p = (const float*)&wb_;
      const float* ba_p = (const float*)&ba; const float* bb_p = (const float*)&bb_;
      __hip_bfloat16 tmp[8];
#pragma unroll
      for (int j = 0; j < 4; j++) {
        tmp[j]     = __float2bfloat16((va[j]   - mean) * rstd * wa_p[j] + ba_p[j]);
        tmp[j + 4] = __float2bfloat16((va[j+4] - mean) * rstd * wb_p[j] + bb_p[j]);
      }
      int slot = p * 8 + sub;
      int ss = slot ^ (row & 7);
      *(uint4*)(a_lds + row * 384 + ss * 16) = *(uint4*)tmp;
    }
  }
  __syncthreads();                        // full drain: LN + W0 + bias visible

  int m0 = wv * 16;
  short8 afr[6];
#pragma unroll
  for (int kt = 0; kt < 6; kt++) {
    int ra = m0 + lc;
    afr[kt] = *(const short8*)(a_lds + ra * 384 + ((kt * 4 + lr) ^ (ra & 7)) * 16);
  }
  bar_lg();                               // a_lds free -> W buf1

#pragma unroll
  for (int i = 0; i < 3; i++) {
    int ii = i * 8 + wv;
    int p = ii * 1024 + lane * 16;
    int row = p / 384, cb = p - row * 384;
    int sc = (cb >> 4) ^ (row & 7);
    gload16(Wc + (long)(64 + row) * 384 + sc * 16, a_lds + ii * 1024);
  }

  for (int pn = 0; pn < 9; pn++) {
    char* wcur = (pn & 1) ? a_lds : w_lds;
    if (pn == 1) bar_vm7(); else if (pn == 8) bar_vm8(); else bar_vm11();
    floatx4 acc[4];
#pragma unroll
    for (int cf = 0; cf < 4; cf++) acc[cf] = {0.f, 0.f, 0.f, 0.f};
#pragma unroll
    for (int kt = 0; kt < 6; kt++)
#pragma unroll
      for (int cf = 0; cf < 4; cf++) {
        int rb = cf * 16 + lc;
        short8 wfr = *(const short8*)(wcur + rb * 384 + ((kt * 4 + lr) ^ (rb & 7)) * 16);
        acc[cf] = __builtin_amdgcn_mfma_f32_16x16x32_bf16(wfr, afr[kt], acc[cf], 0, 0, 0);
      }
    bar_lg();                             // all waves done reading wcur
    if (pn < 7) {
#pragma unroll
      for (int i = 0; i < 3; i++) {
        int ii = i * 8 + wv;
        int p = ii * 1024 + lane * 16;
        int row = p / 384, cb = p - row * 384;
        int sc = (cb >> 4) ^ (row & 7);
        gload16(Wc + (long)((pn + 2) * 64 + row) * 384 + sc * 16, wcur + ii * 1024);
      }
    }
    int sec = pn / 3;
    __hip_bfloat16* dst = (sec == 0) ? oq : ((sec == 1) ? okk : ov);
    float scale = (sec == 0) ? ATT_SCALE : 1.0f;
#pragma unroll
    for (int cf = 0; cf < 4; cf++) {
      int colb = pn * 64 + cf * 16 + lr4;
      float4 bb = *(const float4*)(bias_lds + colb);
      int c0 = colb - sec * 192;
      int head = c0 >> 5, ch = c0 & 31;
      long row = row0 + m0 + lc;
      __hip_bfloat16 tmp[4];
      tmp[0] = __float2bfloat16((acc[cf][0] + bb.x) * scale);
      tmp[1] = __float2bfloat16((acc[cf][1] + bb.y) * scale);
      tmp[2] = __float2bfloat16((acc[cf][2] + bb.z) * scale);
      tmp[3] = __float2bfloat16((acc[cf][3] + bb.w) * scale);
      *(s4b*)(dst + ((long)head * L_TOK + row) * 32 + ch) = *(s4b*)tmp;
    }
  }
}

// ---------------- GEMM (proj): full-K LDS stage, swapped epilogue ------------
__global__ __launch_bounds__(256) void proj_kernel(
    const __hip_bfloat16* __restrict__ A, const __hip_bfloat16* __restrict__ BT,
    const float* __restrict__ cbias, const float* __restrict__ xin,
    float* __restrict__ xout, int sz, int sh, int sw)
{
  __shared__ __hip_bfloat16 a_lds[128 * 192];
  __shared__ __hip_bfloat16 b_lds[64 * 192];
  int tid = threadIdx.x, lane = tid & 63, wv = tid >> 6;
  int wm = wv >> 1, wn = wv & 1;
  int lc = lane & 15, lr = lane >> 4, lr4 = lr * 4;
  long rowBase = (long)blockIdx.x * 128;
  int colBase = blockIdx.y * 64;
  floatx4 acc[4][2];
#pragma unroll
  for (int i = 0; i < 4; i++)
#pragma unroll
    for (int j = 0; j < 2; j++) acc[i][j] = {0.f, 0.f, 0.f, 0.f};

  const char* Ac = (const char*)A;
  const char* Bc = (const char*)BT;

#pragma unroll
  for (int i = 0; i < 12; i++) {
    int ii = i * 4 + wv;
    int p = ii * 1024 + lane * 16;
    int row = p / 384, cb = p - row * 384;
    int sc = (cb >> 4) ^ (row & 7);
    int ch = sc * 8; int head = ch >> 5;
    const char* g = Ac + (((long)head * L_TOK + rowBase + row) * 32 + (ch & 31)) * 2;
    gload16(g, (char*)a_lds + ii * 1024);
  }
#pragma unroll
  for (int i = 0; i < 6; i++) {
    int ii = i * 4 + wv;
    int p = ii * 1024 + lane * 16;
    int row = p / 384, cb = p - row * 384;
    int sc = (cb >> 4) ^ (row & 7);
    const char* g = Bc + (colBase + row) * (long)192 * 2 + sc * 16;
    gload16(g, (char*)b_lds + ii * 1024);
  }
  __syncthreads();
#pragma unroll
  for (int kt = 0; kt < 6; kt++) {
    short8 bfr[2];
#pragma unroll
    for (int fn = 0; fn < 2; fn++) {
      int rb = wn * 32 + fn * 16 + lc;
      bfr[fn] = *(const short8*)((const char*)b_lds + rb * 384 + ((kt * 4 + lr) ^ (rb & 7)) * 16);
    }
#pragma unroll
    for (int fm = 0; fm < 4; fm++) {
      int ra = wm * 64 + fm * 16 + lc;
      short8 afr = *(const short8*)((const char*)a_lds + ra * 384 + ((kt * 4 + lr) ^ (ra & 7)) * 16);
#pragma unroll
      for (int fn = 0; fn < 2; fn++)
        acc[fm][fn] = __builtin_amdgcn_mfma_f32_16x16x32_bf16(bfr[fn], afr, acc[fm][fn], 0, 0, 0);
    }
  }

#pragma unroll
  for (int fm = 0; fm < 4; fm++) {
    long row = rowBase + wm * 64 + fm * 16 + lc;
    int dsti = win_to_spatial((int)row, sz, sh, sw);
#pragma unroll
    for (int fn = 0; fn < 2; fn++) {
      int colb = colBase + wn * 32 + fn * 16 + lr4;
      float4 cb4 = *(const float4*)(cbias + colb);
      long di = (long)dsti * 192 + colb;
      float4 xv = *(const float4*)(xin + di);
      float4 ov;
      ov.x = acc[fm][fn][0] + cb4.x + xv.x;
      ov.y = acc[fm][fn][1] + cb4.y + xv.y;
      ov.z = acc[fm][fn][2] + cb4.z + xv.z;
      ov.w = acc[fm][fn][3] + cb4.w + xv.w;
      *(float4*)(xout + di) = ov;
    }
  }
}

// ---------------- MLP1: fused LN2 + (A @ W1 + b1) + gelu -> T ----------------
__global__ __launch_bounds__(256) void mlp1_kernel(
    const float* __restrict__ x, const float* __restrict__ nw,
    const float* __restrict__ nb,
    const __hip_bfloat16* __restrict__ w1T, const float* __restrict__ b1,
    __hip_bfloat16* __restrict__ T)
{
  __shared__ char a_lds[64 * 384];
  __shared__ char w_lds[64 * 384];
  __shared__ float b1_lds[768];

  int tid = threadIdx.x, lane = tid & 63, wv = tid >> 6;
  int lc = lane & 15, lr = lane >> 4, lr4 = lr * 4;
  long row0 = (long)blockIdx.x * 64;
  const char* Wc = (const char*)w1T;

#pragma unroll
  for (int i = 0; i < 6; i++) {
    int ii = i * 4 + wv;
    int p = ii * 1024 + lane * 16;
    int row = p / 384, cb = p - row * 384;
    int sc = (cb >> 4) ^ (row & 7);
    gload16(Wc + (long)row * 384 + sc * 16, w_lds + ii * 1024);
  }
  if (tid < 192) *(float4*)(b1_lds + tid * 4) = *(const float4*)(b1 + tid * 4);

#pragma unroll
  for (int rg = 0; rg < 2; rg++) {
    int row = rg * 32 + (tid >> 3), sub = tid & 7;
    const float* xp = x + (row0 + row) * 192;
    float4 v[6];
#pragma unroll
    for (int p = 0; p < 3; p++) {
      v[2*p]   = *(const float4*)(xp + p * 64 + sub * 8);
      v[2*p+1] = *(const float4*)(xp + p * 64 + sub * 8 + 4);
    }
    float s = 0.f, sq = 0.f;
#pragma unroll
    for (int i = 0; i < 6; i++) {
      s  += v[i].x + v[i].y + v[i].z + v[i].w;
      sq += v[i].x*v[i].x + v[i].y*v[i].y + v[i].z*v[i].z + v[i].w*v[i].w;
    }
    for (int m = 1; m < 8; m <<= 1) { s += __shfl_xor(s, m); sq += __shfl_xor(sq, m); }
    float mean = s * (1.0f/192.0f);
    float var  = sq * (1.0f/192.0f) - mean * mean;
    float rstd = rsqrtf(var + 1e-5f);
#pragma unroll
    for (int p = 0; p < 3; p++) {
      int ch0 = p * 64 + sub * 8;
      float4 wa = *(const float4*)(nw + ch0), wb_ = *(const float4*)(nw + ch0 + 4);
      float4 ba = *(const float4*)(nb + ch0), bb_ = *(const float4*)(nb + ch0 + 4);
      const float* va = (const float*)&v[2*p];
      const float* wa_p = (const float*)&wa; const float* wb_p = (const float*)&wb_;
      const float* ba_p = (const float*)&ba; const float* bb_p = (const float*)&bb_;
      __hip_bfloat16 tmp[8];
#pragma unroll
      for (int j = 0; j < 4; j++) {
        tmp[j]     = __float2bfloat16((va[j]   - mean) * rstd * wa_p[j] + ba_p[j]);
        tmp[j + 4] = __float2bfloat16((va[j+4] - mean) * rstd * wb_p[j] + bb_p[j]);
      }
      int slot = p * 8 + sub;
      int ss = slot ^ (row & 7);
      *(uint4*)(a_lds + row * 384 + ss * 16) = *(uint4*)tmp;
    }
  }
  __syncthreads();

  int m0 = wv * 16;
  short8 afr[6];
#pragma unroll
  for (int kt = 0; kt < 6; kt++) {
    int ra = m0 + lc;
    afr[kt] = *(const short8*)(a_lds + ra * 384 + ((kt * 4 + lr) ^ (ra & 7)) * 16);
  }
  bar_lg();

#pragma unroll
  for (int i = 0; i < 6; i++) {
    int ii = i * 4 + wv;
    int p = ii * 1024 + lane * 16;
    int row = p / 384, cb = p - row * 384;
    int sc = (cb >> 4) ^ (row & 7);
    gload16(Wc + (long)(64 + row) * 384 + sc * 16, a_lds + ii * 1024);
  }

  for (int pn = 0; pn < 12; pn++) {
    char* wcur = (pn & 1) ? a_lds : w_lds;
    if (pn == 0) bar_vm6();
    else if (pn == 1) bar_vm10();
    else if (pn == 11) bar_vm8();
    else bar_vm14();
    floatx4 acc[4];
#pragma unroll
    for (int cf = 0; cf < 4; cf++) acc[cf] = {0.f, 0.f, 0.f, 0.f};
#pragma unroll
    for (int kt = 0; kt < 6; kt++)
#pragma unroll
      for (int cf = 0; cf < 4; cf++) {
        int rb = cf * 16 + lc;
        short8 wfr = *(const short8*)(wcur + rb * 384 + ((kt * 4 + lr) ^ (rb & 7)) * 16);
        acc[cf] = __builtin_amdgcn_mfma_f32_16x16x32_bf16(wfr, afr[kt], acc[cf], 0, 0, 0);
      }
    bar_lg();
    if (pn < 10) {
#pragma unroll
      for (int i = 0; i < 6; i++) {
        int ii = i * 4 + wv;
        int p = ii * 1024 + lane * 16;
        int row = p / 384, cb = p - row * 384;
        int sc = (cb >> 4) ^ (row & 7);
        gload16(Wc + (long)((pn + 2) * 64 + row) * 384 + sc * 16, wcur + ii * 1024);
      }
    }
#pragma unroll
    for (int cf = 0; cf < 4; cf++) {
      int colb = pn * 64 + cf * 16 + lr4;
      float4 bb = *(const float4*)(b1_lds + colb);
      long row = row0 + m0 + lc;
      __hip_bfloat16 tmp[4];
      tmp[0] = __float2bfloat16(gelu_fast(acc[cf][0] + bb.x));
      tmp[1] = __float2bfloat16(gelu_fast(acc[cf][1] + bb.y));
      tmp[2] = __float2bfloat16(gelu_fast(acc[cf][2] + bb.z));
      tmp[3] = __float2bfloat16(gelu_fast(acc[cf][3] + bb.w));
      *(s4b*)(T + row * 768 + colb) = *(s4b*)tmp;
    }
  }
}

// ---------------- MLP2: O = T @ W2 + b2 + x (residual) ----------------------
__global__ __launch_bounds__(256) void mlp2_kernel(
    const __hip_bfloat16* __restrict__ T, const __hip_bfloat16* __restrict__ w2T,
    const float* __restrict__ b2, const float* __restrict__ x,
    float* __restrict__ out)
{
  __shared__ char a_lds[64 * 384];
  __shared__ char w_lds0[64 * 384];
  __shared__ char w_lds1[64 * 384];

  int tid = threadIdx.x, lane = tid & 63, wv = tid >> 6;
  int lc = lane & 15, lr = lane >> 4, lr4 = lr * 4;
  long row0 = (long)blockIdx.x * 64;
  const char* Ac = (const char*)T;
  const char* Wc = (const char*)w2T;
  int m0 = wv * 16;

  floatx4 acc[3][4];
#pragma unroll
  for (int np = 0; np < 3; np++)
#pragma unroll
    for (int cf = 0; cf < 4; cf++) acc[np][cf] = {0.f, 0.f, 0.f, 0.f};

  int s_ii = lane * 16;
#define STAGE_A(KP)                                                          \
  {                                                                          \
    _Pragma("unroll")                                                        \
    for (int i = 0; i < 6; i++) {                                            \
      int ii = i * 4 + wv;                                                   \
      int p = ii * 1024 + s_ii;                                              \
      int row = p / 384, cb = p - row * 384;                                 \
      int sc = (cb >> 4) ^ (row & 7);                                        \
      gload16(Ac + (row0 + row) * 1536 + (KP) * 384 + sc * 16,               \
              a_lds + ii * 1024);                                            \
    }                                                                        \
  }
#define STAGE_W(KP, NP, BUF)                                                 \
  {                                                                          \
    _Pragma("unroll")                                                        \
    for (int i = 0; i < 6; i++) {                                            \
      int ii = i * 4 + wv;                                                   \
      int p = ii * 1024 + s_ii;                                              \
      int row = p / 384, cb = p - row * 384;                                 \
      int sc = (cb >> 4) ^ (row & 7);                                        \
      gload16(Wc + (long)((NP) * 64 + row) * 1536 + (KP) * 384 + sc * 16,    \
              (BUF) + ii * 1024);                                            \
    }                                                                        \
  }

  STAGE_A(0);
  STAGE_W(0, 0, w_lds0);
  __syncthreads();
  STAGE_W(0, 1, w_lds1);

#pragma unroll
  for (int kp = 0; kp < 4; kp++) {
    if (kp) bar_vm12();
    short8 afr[6];
#pragma unroll
    for (int kt = 0; kt < 6; kt++) {
      int ra = m0 + lc;
      afr[kt] = *(const short8*)(a_lds + ra * 384 + ((kt * 4 + lr) ^ (ra & 7)) * 16);
    }
    bar_lg();
    if (kp < 3) STAGE_A(kp + 1);

#pragma unroll
    for (int np = 0; np < 3; np++) {
      int g = 3 * kp + np;
      const char* wcur = (g & 1) ? w_lds1 : w_lds0;
      if (g == 11) bar_vm0();
      else if (np == 2 || kp == 3) bar_vm6();
      else bar_vm12();
#pragma unroll
      for (int kt = 0; kt < 6; kt++)
#pragma unroll
        for (int cf = 0; cf < 4; cf++) {
          int rb = cf * 16 + lc;
          short8 wfr = *(const short8*)(wcur + rb * 384 + ((kt * 4 + lr) ^ (rb & 7)) * 16);
          acc[np][cf] = __builtin_amdgcn_mfma_f32_16x16x32_bf16(wfr, afr[kt], acc[np][cf], 0, 0, 0);
        }
      bar_lg();
      int gn = g + 2;
      if (gn < 12) {
        char* bnx = (gn & 1) ? w_lds1 : w_lds0;
        int kpn = gn / 3, npn = gn - kpn * 3;
        STAGE_W(kpn, npn, bnx);
      }
    }
  }

#pragma unroll
  for (int np = 0; np < 3; np++)
#pragma unroll
    for (int cf = 0; cf < 4; cf++) {
      int colb = np * 64 + cf * 16 + lr4;
      long row = row0 + m0 + lc;
      float4 bb = *(const float4*)(b2 + colb);
      float4 xv = *(const float4*)(x + row * 192 + colb);
      float4 ov;
      ov.x = acc[np][cf][0] + bb.x + xv.x;
      ov.y = acc[np][cf][1] + bb.y + xv.y;
      ov.z = acc[np][cf][2] + bb.z + xv.z;
      ov.w = acc[np][cf][3] + bb.w + xv.w;
      *(float4*)(out + row * 192 + colb) = ov;
    }
#undef STAGE_A
#undef STAGE_W
}

// ---------------- attention: 3-wave blocks (chunk, half, third) --------------
// Per-wave code identical to r21; block granularity 9 waves -> 3 waves so the
// scheduler can co-resident ~6 blocks/CU (18 waves) instead of 1x9.
// V staged per block (3x redundant across thirds; L2-absorbed).
__global__ __launch_bounds__(192) void attn_kernel(
    const __hip_bfloat16* __restrict__ q, const __hip_bfloat16* __restrict__ k,
    const __hip_bfloat16* __restrict__ v, const __hip_bfloat16* __restrict__ bias_bf,
    __hip_bfloat16* __restrict__ o, int masked)
{
  __shared__ __hip_bfloat16 vT[2][32 * 168];    // 21.5 KB
  __shared__ __hip_bfloat16 pS[3][16 * 40];     // 3.8 KB wave-private P chunk

  int bid = blockIdx.x;                 // 0..2303
  int third = bid / 768;                // 0..2
  int rem = bid - third * 768;
  int chunk = rem % 384, half = rem / 384;
  int wt = chunk / 6, head = chunk - wt * 6;

  int tid = threadIdx.x, wv = tid >> 6, lane = tid & 63;
  int lr = lane >> 4, lc = lane & 15, lr4 = lr * 4;
  const __hip_bfloat16 zb = __float2bfloat16(0.0f);
  int rt = third * 3 + wv;              // 0..8

  s4b bias_r[9];
  {
    const __hip_bfloat16* bp = bias_bf + (long)chunk * 20736;
#pragma unroll
    for (int c = 0; c < 9; c++)
      bias_r[c] = *(const s4b*)(bp + (c * 16 + lc) * 144 + rt * 16 + lr4);
  }

  int w0 = wt * 16 + half * 8;
  long hb = (long)head * L_TOK * 32;
  {
    long base0 = hb + (long)w0 * 144 * 32;
#pragma unroll
    for (int i = 0; i < 3; i++) {
      int id = tid + i * 192;           // 0..575
      int tk = id >> 2, c = id & 3;
      uint4 raw = *(const uint4*)(v + base0 + tk * 32 + c * 8);
      __hip_bfloat16 tmp[8]; *(uint4*)tmp = raw;
#pragma unroll
      for (int j = 0; j < 8; j++) vT[0][(c * 8 + j) * 168 + tk] = tmp[j];
    }
  }
  for (int id = tid; id < 1024; id += 192)   // zero vT pad cols 144..159 (both bufs)
    vT[id >> 9][((id >> 4) & 31) * 168 + 144 + (id & 15)] = zb;

  int sign_[4], sigm_[9];
#pragma unroll
  for (int r = 0; r < 4; r++) {
    int p = rt * 16 + lr4 + r;
    int iz = p / 72; int rem2 = p - iz * 72; int ih = rem2 / 12; int iw = rem2 - ih * 12;
    sign_[r] = iz | ((ih >= 3) << 1) | ((iw >= 6) << 2);
  }
#pragma unroll
  for (int c = 0; c < 9; c++) {
    int p = c * 16 + lc;
    int iz = p / 72; int rem2 = p - iz * 72; int ih = rem2 / 12; int iw = rem2 - ih * 12;
    sigm_[c] = iz | ((ih >= 3) << 1) | ((iw >= 6) << 2);
  }
  bar_lg();                               // prologue ds_writes visible (3 waves)

  __hip_bfloat16* pw = &pS[wv][0];
  const floatx4 z4 = {0.f, 0.f, 0.f, 0.f};
  int cur = 0;

  for (int wi = 0; wi < 8; wi++) {
    int w_ = w0 + wi;
    long base = hb + (long)w_ * 144 * 32;
    uint4 vreg[3];
    if (wi < 7) {
#pragma unroll
      for (int i = 0; i < 3; i++) {
        int id = tid + i * 192;
        vreg[i] = *(const uint4*)(v + base + 144 * 32 + (id >> 2) * 32 + (id & 3) * 8);
      }
    }

    int g = 0;
    if (masked) {
      int nz = w_ >> 8, nh = (w_ >> 4) & 15, nw = w_ & 15;
      g = (nz == 3 ? 1 : 0) | (nh == 15 ? 2 : 0) | (nw == 15 ? 4 : 0);
    }

    short8 qf = *(const short8*)(q + base + (rt * 16 + lc) * 32 + lr * 8);
    floatx4 s[9];
    __builtin_amdgcn_s_setprio(1);
#pragma unroll
    for (int c = 0; c < 9; c++) {
      short8 kf = *(const short8*)(k + base + (c * 16 + lc) * 32 + lr * 8);
      s[c] = __builtin_amdgcn_mfma_f32_16x16x32_bf16(qf, kf, z4, 0, 0, 0);
    }
    __builtin_amdgcn_s_setprio(0);

    float rmax[4] = {-1e30f, -1e30f, -1e30f, -1e30f};
#pragma unroll
    for (int c = 0; c < 9; c++) {
      __hip_bfloat16 bb[4];
      *(s4b*)bb = bias_r[c];
#pragma unroll
      for (int r = 0; r < 4; r++) {
        float val = s[c][r] + __bfloat162float(bb[r]);
        if ((sign_[r] ^ sigm_[c]) & g) val -= 100.0f;
        s[c][r] = val;
        rmax[r] = fmaxf(rmax[r], val);
      }
    }
#pragma unroll
    for (int r = 0; r < 4; r++)
      for (int mm = 1; mm < 16; mm <<= 1) rmax[r] = fmaxf(rmax[r], __shfl_xor(rmax[r], mm));
    float rsum[4] = {0.f, 0.f, 0.f, 0.f};
#pragma unroll
    for (int c = 0; c < 9; c++)
#pragma unroll
      for (int r = 0; r < 4; r++) {
        float p = __expf(s[c][r] - rmax[r]);
        s[c][r] = p; rsum[r] += p;
      }
#pragma unroll
    for (int r = 0; r < 4; r++)
      for (int mm = 1; mm < 16; mm <<= 1) rsum[r] += __shfl_xor(rsum[r], mm);

    // V(wi+1) -> vT[cur^1] (safe: its last readers ran in window wi-1)
    if (wi < 7) {
#pragma unroll
      for (int i = 0; i < 3; i++) {
        int id = tid + i * 192;
        int tk = id >> 2, c = id & 3;
        __hip_bfloat16 tmp[8]; *(uint4*)tmp = vreg[i];
#pragma unroll
        for (int j = 0; j < 8; j++) vT[cur ^ 1][(c * 8 + j) * 168 + tk] = tmp[j];
      }
    }

    // PV in 5 chunks of k=32: write P chunk (wave-private), read pa, 2 MFMA.
    floatx4 oacc[2] = {z4, z4};
#pragma unroll
    for (int t = 0; t < 5; t++) {
      if (t < 4) {
#pragma unroll
        for (int h2 = 0; h2 < 2; h2++) {
          int c = 2 * t + h2;
#pragma unroll
          for (int r = 0; r < 4; r++)
            pw[(lr4 + r) * 40 + h2 * 16 + lc] = __float2bfloat16(s[c][r]);
        }
      } else {
#pragma unroll
        for (int r = 0; r < 4; r++) {
          pw[(lr4 + r) * 40 + lc] = __float2bfloat16(s[8][r]);
          pw[(lr4 + r) * 40 + 16 + lc] = zb;
        }
      }
      short8 pa = *(short8*)(&pw[lc * 40 + lr * 8]);
      __builtin_amdgcn_s_setprio(1);
#pragma unroll
      for (int vt = 0; vt < 2; vt++) {
        short8 vbf = *(short8*)(&vT[cur][(vt * 16 + lc) * 168 + t * 32 + lr * 8]);
        oacc[vt] = __builtin_amdgcn_mfma_f32_16x16x32_bf16(pa, vbf, oacc[vt], 0, 0, 0);
      }
      __builtin_amdgcn_s_setprio(0);
    }
    float inv[4];
#pragma unroll
    for (int r = 0; r < 4; r++) inv[r] = 1.0f / rsum[r];
#pragma unroll
    for (int vt = 0; vt < 2; vt++)
#pragma unroll
      for (int r = 0; r < 4; r++)
        o[base + (rt * 16 + lr4 + r) * 32 + vt * 16 + lc] =
            __float2bfloat16(oacc[vt][r] * inv[r]);

    bar_lg();                             // publish vT[cur^1]; sync 3 waves
    cur ^= 1;
  }
}

// ---------------- host orchestration ----------------------------------------
extern "C" void kernel_launch(void* const* d_in, const int* in_sizes, int n_in,
                              void* d_out, int out_size, void* d_ws, size_t ws_size,
                              hipStream_t stream)
{
  const float* x_in  = (const float*)d_in[0];
  const float* n1w   = (const float*)d_in[1];
  const float* n1b   = (const float*)d_in[2];
  const float* qkvw  = (const float*)d_in[3];
  const float* qkvb  = (const float*)d_in[4];
  const float* btab  = (const float*)d_in[5];
  const float* projw = (const float*)d_in[6];
  const float* projb = (const float*)d_in[7];
  const float* n2w   = (const float*)d_in[8];
  const float* n2b   = (const float*)d_in[9];
  const float* w1    = (const float*)d_in[10];
  const float* b1    = (const float*)d_in[11];
  const float* w2    = (const float*)d_in[12];
  const float* b2    = (const float*)d_in[13];

  char* ws = (char*)d_ws;
  float* x            = (float*)(ws);                          // 113,246,208 B
  __hip_bfloat16* qb  = (__hip_bfloat16*)(ws + 169869312);     // q,k,v,o head-major
  __hip_bfloat16* kb  = qb + 28311552;
  __hip_bfloat16* vb  = kb + 28311552;
  __hip_bfloat16* ob  = vb + 28311552;
  __hip_bfloat16* Tb  = qb;                                    // MLP intermediate reuses region
  __hip_bfloat16* biasb = (__hip_bfloat16*)(ws + 396361728);
  __hip_bfloat16* wqkvT  = (__hip_bfloat16*)(ws + 428212224);
  __hip_bfloat16* wprojT = wqkvT + 110592;
  __hip_bfloat16* w1T    = wprojT + 36864;
  __hip_bfloat16* w2T    = w1T + 147456;

  for (int layer = 0; layer < 2; layer++) {
    int sz = layer ? 1 : 0, sh = layer ? 3 : 0, sw = layer ? 6 : 0;
    int masked = layer;
    const float* xsrc = (layer == 0) ? x_in : x;   // residual source

    convT4_kernel<<<1728, 256, 0, stream>>>(
        qkvw + (long)layer * 110592, projw + (long)layer * 36864,
        w1 + (long)layer * 147456, w2 + (long)layer * 147456,
        wqkvT, wprojT, w1T, w2T);
    biaspre_kernel<<<dim3(384, 9), 256, 0, stream>>>(btab + (long)layer * 3312 * 384, biasb);

    qkv_kernel<<<1152, 512, 0, stream>>>(
        xsrc, n1w + layer * 192, n1b + layer * 192, wqkvT, qkvb + layer * 576,
        qb, kb, vb, sz, sh, sw);
    attn_kernel<<<2304, 192, 0, stream>>>(qb, kb, vb, biasb, ob, masked);
    proj_kernel<<<dim3(1152, 3), 256, 0, stream>>>(
        ob, wprojT, projb + layer * 192, xsrc, x, sz, sh, sw);
    mlp1_kernel<<<2304, 256, 0, stream>>>(
        x, n2w + layer * 192, n2b + layer * 192, w1T, b1 + layer * 768, Tb);
    mlp2_kernel<<<2304, 256, 0, stream>>>(
        Tb, w2T, b2 + layer * 192, x, (layer == 0) ? x : (float*)d_out);
  }
}

// Round 23
// 1152.673 us; speedup vs baseline: 1.0784x; 1.0784x over previous
//
#include <hip/hip_runtime.h>
#include <hip/hip_bf16.h>

typedef short short8 __attribute__((ext_vector_type(8)));
typedef short s4b __attribute__((ext_vector_type(4)));
typedef float floatx4 __attribute__((ext_vector_type(4)));
typedef unsigned int u32;

#define DEVFN static __device__ __forceinline__

constexpr int L_TOK = 147456;          // 8*96*192
constexpr float ATT_SCALE = 0.17677669529663687f;  // 32^-0.5

DEVFN int win_to_spatial(int t, int sz, int sh, int sw) {
  int w_ = t / 144;
  int n  = t - w_ * 144;
  int nz = w_ >> 8, nh = (w_ >> 4) & 15, nw = w_ & 15;
  int iz = n / 72; int rem = n - iz * 72;
  int ih = rem / 12; int iw = rem - ih * 12;
  int z = nz * 2 + iz + sz;  if (z >= 8)   z -= 8;
  int h = nh * 6 + ih + sh;  if (h >= 96)  h -= 96;
  int wc = nw * 12 + iw + sw; if (wc >= 192) wc -= 192;
  return (z * 96 + h) * 192 + wc;
}

DEVFN void gload16(const void* g, void* l) {
  __builtin_amdgcn_global_load_lds(
      (const __attribute__((address_space(1))) u32*)(g),
      (__attribute__((address_space(3))) u32*)(l), 16, 0, 0);
}

// counted-wait barriers (no vmcnt-0 drain)
DEVFN void bar_vm14() { asm volatile("s_waitcnt vmcnt(14)\n\ts_barrier" ::: "memory"); }
DEVFN void bar_vm12() { asm volatile("s_waitcnt vmcnt(12)\n\ts_barrier" ::: "memory"); }
DEVFN void bar_vm11() { asm volatile("s_waitcnt vmcnt(11)\n\ts_barrier" ::: "memory"); }
DEVFN void bar_vm10() { asm volatile("s_waitcnt vmcnt(10)\n\ts_barrier" ::: "memory"); }
DEVFN void bar_vm8()  { asm volatile("s_waitcnt vmcnt(8)\n\ts_barrier"  ::: "memory"); }
DEVFN void bar_vm7()  { asm volatile("s_waitcnt vmcnt(7)\n\ts_barrier"  ::: "memory"); }
DEVFN void bar_vm6()  { asm volatile("s_waitcnt vmcnt(6)\n\ts_barrier"  ::: "memory"); }
DEVFN void bar_vm0()  { asm volatile("s_waitcnt vmcnt(0)\n\ts_barrier"  ::: "memory"); }
DEVFN void bar_lg()   { asm volatile("s_waitcnt lgkmcnt(0)\n\ts_barrier" ::: "memory"); }

DEVFN float gelu_fast(float x) {
  float e = __expf(-1.702f * x);
  return x * __fdividef(1.0f, 1.0f + e);
}

// ---------------- fused weight convert+transpose (all 4 weights, 1 launch) ---
__global__ __launch_bounds__(256) void convT4_kernel(
    const float* __restrict__ in0, const float* __restrict__ in1,
    const float* __restrict__ in2, const float* __restrict__ in3,
    __hip_bfloat16* __restrict__ o0, __hip_bfloat16* __restrict__ o1,
    __hip_bfloat16* __restrict__ o2, __hip_bfloat16* __restrict__ o3)
{
  int idx = blockIdx.x * 256 + threadIdx.x;   // 0..442367
  const float* in; __hip_bfloat16* out; int K, N;
  if (idx < 110592)      { in = in0; out = o0; K = 192; N = 576; }
  else if (idx < 147456) { in = in1; out = o1; K = 192; N = 192; idx -= 110592; }
  else if (idx < 294912) { in = in2; out = o2; K = 192; N = 768; idx -= 147456; }
  else                   { in = in3; out = o3; K = 768; N = 192; idx -= 294912; }
  int n = idx / K, k = idx - n * K;
  out[idx] = __float2bfloat16(in[(long)k * N + n]);
}

// ---------------- bias expansion, TRANSPOSED: out[t][m][n] -------------------
__global__ __launch_bounds__(256) void biaspre_kernel(
    const float* __restrict__ tab, __hip_bfloat16* __restrict__ out)
{
  int t = blockIdx.x;
  int e0 = blockIdx.y * 2304;
  for (int e = e0 + threadIdx.x; e < e0 + 2304; e += 256) {
    int m = e / 144, n = e - m * 144;
    int izn = n / 72, rn = n - izn * 72, ihn = rn / 12, iwn = rn - ihn * 12;
    int izm = m / 72, rm = m - izm * 72, ihm = rm / 12, iwm = rm - ihm * 12;
    int idx = (izn + 2 * izm) * 828 + (ihn + 6 * ihm) * 23 + (iwn - iwm + 11);
    out[(long)t * 20736 + e] = __float2bfloat16(tab[(long)idx * 384 + t]);
  }
}

// ---------------- fused LN1 + QKV GEMM -> head-major q/k/v (512-thr) ---------
__global__ __launch_bounds__(512) void qkv_kernel(
    const float* __restrict__ x, const float* __restrict__ nw,
    const float* __restrict__ nb,
    const __hip_bfloat16* __restrict__ wqkvT, const float* __restrict__ qbias,
    __hip_bfloat16* __restrict__ oq, __hip_bfloat16* __restrict__ okk,
    __hip_bfloat16* __restrict__ ov, int sz, int sh, int sw)
{
  __shared__ char a_lds[128 * 384];   // LN tile; first 24KB reused as W buf1
  __shared__ char w_lds[64 * 384];    // W buf0
  __shared__ float bias_lds[576];

  int tid = threadIdx.x, lane = tid & 63, wv = tid >> 6;
  int lc = lane & 15, lr = lane >> 4, lr4 = lr * 4;
  long row0 = (long)blockIdx.x * 128;
  const char* Wc = (const char*)wqkvT;

#pragma unroll
  for (int i = 0; i < 3; i++) {
    int ii = i * 8 + wv;
    int p = ii * 1024 + lane * 16;
    int row = p / 384, cb = p - row * 384;
    int sc = (cb >> 4) ^ (row & 7);
    gload16(Wc + (long)row * 384 + sc * 16, w_lds + ii * 1024);
  }
  if (tid < 144) *(float4*)(bias_lds + tid * 4) = *(const float4*)(qbias + tid * 4);

#pragma unroll
  for (int rg = 0; rg < 2; rg++) {
    int row = rg * 64 + (tid >> 3), sub = tid & 7;
    int src = win_to_spatial((int)(row0 + row), sz, sh, sw);
    const float* xp = x + (long)src * 192;
    float4 v[6];
#pragma unroll
    for (int p = 0; p < 3; p++) {
      v[2*p]   = *(const float4*)(xp + p * 64 + sub * 8);
      v[2*p+1] = *(const float4*)(xp + p * 64 + sub * 8 + 4);
    }
    float s = 0.f, sq = 0.f;
#pragma unroll
    for (int i = 0; i < 6; i++) {
      s  += v[i].x + v[i].y + v[i].z + v[i].w;
      sq += v[i].x*v[i].x + v[i].y*v[i].y + v[i].z*v[i].z + v[i].w*v[i].w;
    }
    for (int m = 1; m < 8; m <<= 1) { s += __shfl_xor(s, m); sq += __shfl_xor(sq, m); }
    float mean = s * (1.0f/192.0f);
    float var  = sq * (1.0f/192.0f) - mean * mean;
    float rstd = rsqrtf(var + 1e-5f);
#pragma unroll
    for (int p = 0; p < 3; p++) {
      int ch0 = p * 64 + sub * 8;
      float4 wa = *(const float4*)(nw + ch0), wb_ = *(const float4*)(nw + ch0 + 4);
      float4 ba = *(const float4*)(nb + ch0), bb_ = *(const float4*)(nb + ch0 + 4);
      const float* va = (const float*)&v[2*p];
      const float* wa_p = (const float*)&wa; const float* wb_p = (const float*)&wb_;
      const float* ba_p = (const float*)&ba; const float* bb_p = (const float*)&bb_;
      __hip_bfloat16 tmp[8];
#pragma unroll
      for (int j = 0; j < 4; j++) {
        tmp[j]     = __float2bfloat16((va[j]   - mean) * rstd * wa_p[j] + ba_p[j]);
        tmp[j + 4] = __float2bfloat16((va[j+4] - mean) * rstd * wb_p[j] + bb_p[j]);
      }
      int slot = p * 8 + sub;
      int ss = slot ^ (row & 7);
      *(uint4*)(a_lds + row * 384 + ss * 16) = *(uint4*)tmp;
    }
  }
  __syncthreads();                        // full drain: LN + W0 + bias visible

  int m0 = wv * 16;
  short8 afr[6];
#pragma unroll
  for (int kt = 0; kt < 6; kt++) {
    int ra = m0 + lc;
    afr[kt] = *(const short8*)(a_lds + ra * 384 + ((kt * 4 + lr) ^ (ra & 7)) * 16);
  }
  bar_lg();                               // a_lds free -> W buf1

#pragma unroll
  for (int i = 0; i < 3; i++) {
    int ii = i * 8 + wv;
    int p = ii * 1024 + lane * 16;
    int row = p / 384, cb = p - row * 384;
    int sc = (cb >> 4) ^ (row & 7);
    gload16(Wc + (long)(64 + row) * 384 + sc * 16, a_lds + ii * 1024);
  }

  for (int pn = 0; pn < 9; pn++) {
    char* wcur = (pn & 1) ? a_lds : w_lds;
    if (pn == 1) bar_vm7(); else if (pn == 8) bar_vm8(); else bar_vm11();
    floatx4 acc[4];
#pragma unroll
    for (int cf = 0; cf < 4; cf++) acc[cf] = {0.f, 0.f, 0.f, 0.f};
#pragma unroll
    for (int kt = 0; kt < 6; kt++)
#pragma unroll
      for (int cf = 0; cf < 4; cf++) {
        int rb = cf * 16 + lc;
        short8 wfr = *(const short8*)(wcur + rb * 384 + ((kt * 4 + lr) ^ (rb & 7)) * 16);
        acc[cf] = __builtin_amdgcn_mfma_f32_16x16x32_bf16(wfr, afr[kt], acc[cf], 0, 0, 0);
      }
    bar_lg();                             // all waves done reading wcur
    if (pn < 7) {
#pragma unroll
      for (int i = 0; i < 3; i++) {
        int ii = i * 8 + wv;
        int p = ii * 1024 + lane * 16;
        int row = p / 384, cb = p - row * 384;
        int sc = (cb >> 4) ^ (row & 7);
        gload16(Wc + (long)((pn + 2) * 64 + row) * 384 + sc * 16, wcur + ii * 1024);
      }
    }
    int sec = pn / 3;
    __hip_bfloat16* dst = (sec == 0) ? oq : ((sec == 1) ? okk : ov);
    float scale = (sec == 0) ? ATT_SCALE : 1.0f;
#pragma unroll
    for (int cf = 0; cf < 4; cf++) {
      int colb = pn * 64 + cf * 16 + lr4;
      float4 bb = *(const float4*)(bias_lds + colb);
      int c0 = colb - sec * 192;
      int head = c0 >> 5, ch = c0 & 31;
      long row = row0 + m0 + lc;
      __hip_bfloat16 tmp[4];
      tmp[0] = __float2bfloat16((acc[cf][0] + bb.x) * scale);
      tmp[1] = __float2bfloat16((acc[cf][1] + bb.y) * scale);
      tmp[2] = __float2bfloat16((acc[cf][2] + bb.z) * scale);
      tmp[3] = __float2bfloat16((acc[cf][3] + bb.w) * scale);
      *(s4b*)(dst + ((long)head * L_TOK + row) * 32 + ch) = *(s4b*)tmp;
    }
  }
}

// ---------------- GEMM (proj): full-K LDS stage, swapped epilogue ------------
__global__ __launch_bounds__(256) void proj_kernel(
    const __hip_bfloat16* __restrict__ A, const __hip_bfloat16* __restrict__ BT,
    const float* __restrict__ cbias, const float* __restrict__ xin,
    float* __restrict__ xout, int sz, int sh, int sw)
{
  __shared__ __hip_bfloat16 a_lds[128 * 192];
  __shared__ __hip_bfloat16 b_lds[64 * 192];
  int tid = threadIdx.x, lane = tid & 63, wv = tid >> 6;
  int wm = wv >> 1, wn = wv & 1;
  int lc = lane & 15, lr = lane >> 4, lr4 = lr * 4;
  long rowBase = (long)blockIdx.x * 128;
  int colBase = blockIdx.y * 64;
  floatx4 acc[4][2];
#pragma unroll
  for (int i = 0; i < 4; i++)
#pragma unroll
    for (int j = 0; j < 2; j++) acc[i][j] = {0.f, 0.f, 0.f, 0.f};

  const char* Ac = (const char*)A;
  const char* Bc = (const char*)BT;

#pragma unroll
  for (int i = 0; i < 12; i++) {
    int ii = i * 4 + wv;
    int p = ii * 1024 + lane * 16;
    int row = p / 384, cb = p - row * 384;
    int sc = (cb >> 4) ^ (row & 7);
    int ch = sc * 8; int head = ch >> 5;
    const char* g = Ac + (((long)head * L_TOK + rowBase + row) * 32 + (ch & 31)) * 2;
    gload16(g, (char*)a_lds + ii * 1024);
  }
#pragma unroll
  for (int i = 0; i < 6; i++) {
    int ii = i * 4 + wv;
    int p = ii * 1024 + lane * 16;
    int row = p / 384, cb = p - row * 384;
    int sc = (cb >> 4) ^ (row & 7);
    const char* g = Bc + (colBase + row) * (long)192 * 2 + sc * 16;
    gload16(g, (char*)b_lds + ii * 1024);
  }
  __syncthreads();
#pragma unroll
  for (int kt = 0; kt < 6; kt++) {
    short8 bfr[2];
#pragma unroll
    for (int fn = 0; fn < 2; fn++) {
      int rb = wn * 32 + fn * 16 + lc;
      bfr[fn] = *(const short8*)((const char*)b_lds + rb * 384 + ((kt * 4 + lr) ^ (rb & 7)) * 16);
    }
#pragma unroll
    for (int fm = 0; fm < 4; fm++) {
      int ra = wm * 64 + fm * 16 + lc;
      short8 afr = *(const short8*)((const char*)a_lds + ra * 384 + ((kt * 4 + lr) ^ (ra & 7)) * 16);
#pragma unroll
      for (int fn = 0; fn < 2; fn++)
        acc[fm][fn] = __builtin_amdgcn_mfma_f32_16x16x32_bf16(bfr[fn], afr, acc[fm][fn], 0, 0, 0);
    }
  }

#pragma unroll
  for (int fm = 0; fm < 4; fm++) {
    long row = rowBase + wm * 64 + fm * 16 + lc;
    int dsti = win_to_spatial((int)row, sz, sh, sw);
#pragma unroll
    for (int fn = 0; fn < 2; fn++) {
      int colb = colBase + wn * 32 + fn * 16 + lr4;
      float4 cb4 = *(const float4*)(cbias + colb);
      long di = (long)dsti * 192 + colb;
      float4 xv = *(const float4*)(xin + di);
      float4 ov;
      ov.x = acc[fm][fn][0] + cb4.x + xv.x;
      ov.y = acc[fm][fn][1] + cb4.y + xv.y;
      ov.z = acc[fm][fn][2] + cb4.z + xv.z;
      ov.w = acc[fm][fn][3] + cb4.w + xv.w;
      *(float4*)(xout + di) = ov;
    }
  }
}

// ---------------- MLP1: fused LN2 + (A @ W1 + b1) + gelu -> T ----------------
__global__ __launch_bounds__(256) void mlp1_kernel(
    const float* __restrict__ x, const float* __restrict__ nw,
    const float* __restrict__ nb,
    const __hip_bfloat16* __restrict__ w1T, const float* __restrict__ b1,
    __hip_bfloat16* __restrict__ T)
{
  __shared__ char a_lds[64 * 384];
  __shared__ char w_lds[64 * 384];
  __shared__ float b1_lds[768];

  int tid = threadIdx.x, lane = tid & 63, wv = tid >> 6;
  int lc = lane & 15, lr = lane >> 4, lr4 = lr * 4;
  long row0 = (long)blockIdx.x * 64;
  const char* Wc = (const char*)w1T;

#pragma unroll
  for (int i = 0; i < 6; i++) {
    int ii = i * 4 + wv;
    int p = ii * 1024 + lane * 16;
    int row = p / 384, cb = p - row * 384;
    int sc = (cb >> 4) ^ (row & 7);
    gload16(Wc + (long)row * 384 + sc * 16, w_lds + ii * 1024);
  }
  if (tid < 192) *(float4*)(b1_lds + tid * 4) = *(const float4*)(b1 + tid * 4);

#pragma unroll
  for (int rg = 0; rg < 2; rg++) {
    int row = rg * 32 + (tid >> 3), sub = tid & 7;
    const float* xp = x + (row0 + row) * 192;
    float4 v[6];
#pragma unroll
    for (int p = 0; p < 3; p++) {
      v[2*p]   = *(const float4*)(xp + p * 64 + sub * 8);
      v[2*p+1] = *(const float4*)(xp + p * 64 + sub * 8 + 4);
    }
    float s = 0.f, sq = 0.f;
#pragma unroll
    for (int i = 0; i < 6; i++) {
      s  += v[i].x + v[i].y + v[i].z + v[i].w;
      sq += v[i].x*v[i].x + v[i].y*v[i].y + v[i].z*v[i].z + v[i].w*v[i].w;
    }
    for (int m = 1; m < 8; m <<= 1) { s += __shfl_xor(s, m); sq += __shfl_xor(sq, m); }
    float mean = s * (1.0f/192.0f);
    float var  = sq * (1.0f/192.0f) - mean * mean;
    float rstd = rsqrtf(var + 1e-5f);
#pragma unroll
    for (int p = 0; p < 3; p++) {
      int ch0 = p * 64 + sub * 8;
      float4 wa = *(const float4*)(nw + ch0), wb_ = *(const float4*)(nw + ch0 + 4);
      float4 ba = *(const float4*)(nb + ch0), bb_ = *(const float4*)(nb + ch0 + 4);
      const float* va = (const float*)&v[2*p];
      const float* wa_p = (const float*)&wa; const float* wb_p = (const float*)&wb_;
      const float* ba_p = (const float*)&ba; const float* bb_p = (const float*)&bb_;
      __hip_bfloat16 tmp[8];
#pragma unroll
      for (int j = 0; j < 4; j++) {
        tmp[j]     = __float2bfloat16((va[j]   - mean) * rstd * wa_p[j] + ba_p[j]);
        tmp[j + 4] = __float2bfloat16((va[j+4] - mean) * rstd * wb_p[j] + bb_p[j]);
      }
      int slot = p * 8 + sub;
      int ss = slot ^ (row & 7);
      *(uint4*)(a_lds + row * 384 + ss * 16) = *(uint4*)tmp;
    }
  }
  __syncthreads();

  int m0 = wv * 16;
  short8 afr[6];
#pragma unroll
  for (int kt = 0; kt < 6; kt++) {
    int ra = m0 + lc;
    afr[kt] = *(const short8*)(a_lds + ra * 384 + ((kt * 4 + lr) ^ (ra & 7)) * 16);
  }
  bar_lg();

#pragma unroll
  for (int i = 0; i < 6; i++) {
    int ii = i * 4 + wv;
    int p = ii * 1024 + lane * 16;
    int row = p / 384, cb = p - row * 384;
    int sc = (cb >> 4) ^ (row & 7);
    gload16(Wc + (long)(64 + row) * 384 + sc * 16, a_lds + ii * 1024);
  }

  for (int pn = 0; pn < 12; pn++) {
    char* wcur = (pn & 1) ? a_lds : w_lds;
    if (pn == 0) bar_vm6();
    else if (pn == 1) bar_vm10();
    else if (pn == 11) bar_vm8();
    else bar_vm14();
    floatx4 acc[4];
#pragma unroll
    for (int cf = 0; cf < 4; cf++) acc[cf] = {0.f, 0.f, 0.f, 0.f};
#pragma unroll
    for (int kt = 0; kt < 6; kt++)
#pragma unroll
      for (int cf = 0; cf < 4; cf++) {
        int rb = cf * 16 + lc;
        short8 wfr = *(const short8*)(wcur + rb * 384 + ((kt * 4 + lr) ^ (rb & 7)) * 16);
        acc[cf] = __builtin_amdgcn_mfma_f32_16x16x32_bf16(wfr, afr[kt], acc[cf], 0, 0, 0);
      }
    bar_lg();
    if (pn < 10) {
#pragma unroll
      for (int i = 0; i < 6; i++) {
        int ii = i * 4 + wv;
        int p = ii * 1024 + lane * 16;
        int row = p / 384, cb = p - row * 384;
        int sc = (cb >> 4) ^ (row & 7);
        gload16(Wc + (long)((pn + 2) * 64 + row) * 384 + sc * 16, wcur + ii * 1024);
      }
    }
#pragma unroll
    for (int cf = 0; cf < 4; cf++) {
      int colb = pn * 64 + cf * 16 + lr4;
      float4 bb = *(const float4*)(b1_lds + colb);
      long row = row0 + m0 + lc;
      __hip_bfloat16 tmp[4];
      tmp[0] = __float2bfloat16(gelu_fast(acc[cf][0] + bb.x));
      tmp[1] = __float2bfloat16(gelu_fast(acc[cf][1] + bb.y));
      tmp[2] = __float2bfloat16(gelu_fast(acc[cf][2] + bb.z));
      tmp[3] = __float2bfloat16(gelu_fast(acc[cf][3] + bb.w));
      *(s4b*)(T + row * 768 + colb) = *(s4b*)tmp;
    }
  }
}

// ---------------- MLP2: O = T @ W2 + b2 + x (residual) ----------------------
__global__ __launch_bounds__(256) void mlp2_kernel(
    const __hip_bfloat16* __restrict__ T, const __hip_bfloat16* __restrict__ w2T,
    const float* __restrict__ b2, const float* __restrict__ x,
    float* __restrict__ out)
{
  __shared__ char a_lds[64 * 384];
  __shared__ char w_lds0[64 * 384];
  __shared__ char w_lds1[64 * 384];

  int tid = threadIdx.x, lane = tid & 63, wv = tid >> 6;
  int lc = lane & 15, lr = lane >> 4, lr4 = lr * 4;
  long row0 = (long)blockIdx.x * 64;
  const char* Ac = (const char*)T;
  const char* Wc = (const char*)w2T;
  int m0 = wv * 16;

  floatx4 acc[3][4];
#pragma unroll
  for (int np = 0; np < 3; np++)
#pragma unroll
    for (int cf = 0; cf < 4; cf++) acc[np][cf] = {0.f, 0.f, 0.f, 0.f};

  int s_ii = lane * 16;
#define STAGE_A(KP)                                                          \
  {                                                                          \
    _Pragma("unroll")                                                        \
    for (int i = 0; i < 6; i++) {                                            \
      int ii = i * 4 + wv;                                                   \
      int p = ii * 1024 + s_ii;                                              \
      int row = p / 384, cb = p - row * 384;                                 \
      int sc = (cb >> 4) ^ (row & 7);                                        \
      gload16(Ac + (row0 + row) * 1536 + (KP) * 384 + sc * 16,               \
              a_lds + ii * 1024);                                            \
    }                                                                        \
  }
#define STAGE_W(KP, NP, BUF)                                                 \
  {                                                                          \
    _Pragma("unroll")                                                        \
    for (int i = 0; i < 6; i++) {                                            \
      int ii = i * 4 + wv;                                                   \
      int p = ii * 1024 + s_ii;                                              \
      int row = p / 384, cb = p - row * 384;                                 \
      int sc = (cb >> 4) ^ (row & 7);                                        \
      gload16(Wc + (long)((NP) * 64 + row) * 1536 + (KP) * 384 + sc * 16,    \
              (BUF) + ii * 1024);                                            \
    }                                                                        \
  }

  STAGE_A(0);
  STAGE_W(0, 0, w_lds0);
  __syncthreads();
  STAGE_W(0, 1, w_lds1);

#pragma unroll
  for (int kp = 0; kp < 4; kp++) {
    if (kp) bar_vm12();
    short8 afr[6];
#pragma unroll
    for (int kt = 0; kt < 6; kt++) {
      int ra = m0 + lc;
      afr[kt] = *(const short8*)(a_lds + ra * 384 + ((kt * 4 + lr) ^ (ra & 7)) * 16);
    }
    bar_lg();
    if (kp < 3) STAGE_A(kp + 1);

#pragma unroll
    for (int np = 0; np < 3; np++) {
      int g = 3 * kp + np;
      const char* wcur = (g & 1) ? w_lds1 : w_lds0;
      if (g == 11) bar_vm0();
      else if (np == 2 || kp == 3) bar_vm6();
      else bar_vm12();
#pragma unroll
      for (int kt = 0; kt < 6; kt++)
#pragma unroll
        for (int cf = 0; cf < 4; cf++) {
          int rb = cf * 16 + lc;
          short8 wfr = *(const short8*)(wcur + rb * 384 + ((kt * 4 + lr) ^ (rb & 7)) * 16);
          acc[np][cf] = __builtin_amdgcn_mfma_f32_16x16x32_bf16(wfr, afr[kt], acc[np][cf], 0, 0, 0);
        }
      bar_lg();
      int gn = g + 2;
      if (gn < 12) {
        char* bnx = (gn & 1) ? w_lds1 : w_lds0;
        int kpn = gn / 3, npn = gn - kpn * 3;
        STAGE_W(kpn, npn, bnx);
      }
    }
  }

#pragma unroll
  for (int np = 0; np < 3; np++)
#pragma unroll
    for (int cf = 0; cf < 4; cf++) {
      int colb = np * 64 + cf * 16 + lr4;
      long row = row0 + m0 + lc;
      float4 bb = *(const float4*)(b2 + colb);
      float4 xv = *(const float4*)(x + row * 192 + colb);
      float4 ov;
      ov.x = acc[np][cf][0] + bb.x + xv.x;
      ov.y = acc[np][cf][1] + bb.y + xv.y;
      ov.z = acc[np][cf][2] + bb.z + xv.z;
      ov.w = acc[np][cf][3] + bb.w + xv.w;
      *(float4*)(out + row * 192 + colb) = ov;
    }
#undef STAGE_A
#undef STAGE_W
}

// ---------------- attention: r19/r21 config (chunked P, vT dbuf, 1 barrier) --
__global__ __launch_bounds__(576) void attn_kernel(
    const __hip_bfloat16* __restrict__ q, const __hip_bfloat16* __restrict__ k,
    const __hip_bfloat16* __restrict__ v, const __hip_bfloat16* __restrict__ bias_bf,
    __hip_bfloat16* __restrict__ o, int masked)
{
  __shared__ __hip_bfloat16 vT[2][32 * 168];    // 21.5 KB
  __shared__ __hip_bfloat16 pS[9][16 * 40];     // 11.5 KB wave-private P chunk

  int bid = blockIdx.x;
  int chunk = bid % 384, half = bid / 384;
  int wt = chunk / 6, head = chunk - wt * 6;

  int tid = threadIdx.x, wv = tid >> 6, lane = tid & 63;
  int lr = lane >> 4, lc = lane & 15, lr4 = lr * 4;
  const __hip_bfloat16 zb = __float2bfloat16(0.0f);
  int rt = wv;

  s4b bias_r[9];
  {
    const __hip_bfloat16* bp = bias_bf + (long)chunk * 20736;
#pragma unroll
    for (int c = 0; c < 9; c++)
      bias_r[c] = *(const s4b*)(bp + (c * 16 + lc) * 144 + rt * 16 + lr4);
  }

  int w0 = wt * 16 + half * 8;
  long hb = (long)head * L_TOK * 32;
  {
    long base0 = hb + (long)w0 * 144 * 32;
    int tk = tid >> 2, c = tid & 3;
    uint4 raw = *(const uint4*)(v + base0 + tk * 32 + c * 8);
    __hip_bfloat16 tmp[8]; *(uint4*)tmp = raw;
#pragma unroll
    for (int j = 0; j < 8; j++) vT[0][(c * 8 + j) * 168 + tk] = tmp[j];
  }
  for (int id = tid; id < 1024; id += 576)   // zero vT pad cols 144..159 (both bufs)
    vT[id >> 9][((id >> 4) & 31) * 168 + 144 + (id & 15)] = zb;

  int sign_[4], sigm_[9];
#pragma unroll
  for (int r = 0; r < 4; r++) {
    int p = rt * 16 + lr4 + r;
    int iz = p / 72; int rem = p - iz * 72; int ih = rem / 12; int iw = rem - ih * 12;
    sign_[r] = iz | ((ih >= 3) << 1) | ((iw >= 6) << 2);
  }
#pragma unroll
  for (int c = 0; c < 9; c++) {
    int p = c * 16 + lc;
    int iz = p / 72; int rem = p - iz * 72; int ih = rem / 12; int iw = rem - ih * 12;
    sigm_[c] = iz | ((ih >= 3) << 1) | ((iw >= 6) << 2);
  }
  bar_lg();

  __hip_bfloat16* pw = &pS[wv][0];
  const floatx4 z4 = {0.f, 0.f, 0.f, 0.f};
  int cur = 0;

  for (int wi = 0; wi < 8; wi++) {
    int w_ = w0 + wi;
    long base = hb + (long)w_ * 144 * 32;
    uint4 vreg;
    if (wi < 7)
      vreg = *(const uint4*)(v + base + 144 * 32 + (tid >> 2) * 32 + (tid & 3) * 8);

    int g = 0;
    if (masked) {
      int nz = w_ >> 8, nh = (w_ >> 4) & 15, nw = w_ & 15;
      g = (nz == 3 ? 1 : 0) | (nh == 15 ? 2 : 0) | (nw == 15 ? 4 : 0);
    }

    short8 qf = *(const short8*)(q + base + (rt * 16 + lc) * 32 + lr * 8);
    floatx4 s[9];
    __builtin_amdgcn_s_setprio(1);
#pragma unroll
    for (int c = 0; c < 9; c++) {
      short8 kf = *(const short8*)(k + base + (c * 16 + lc) * 32 + lr * 8);
      s[c] = __builtin_amdgcn_mfma_f32_16x16x32_bf16(qf, kf, z4, 0, 0, 0);
    }
    __builtin_amdgcn_s_setprio(0);

    float rmax[4] = {-1e30f, -1e30f, -1e30f, -1e30f};
#pragma unroll
    for (int c = 0; c < 9; c++) {
      __hip_bfloat16 bb[4];
      *(s4b*)bb = bias_r[c];
#pragma unroll
      for (int r = 0; r < 4; r++) {
        float val = s[c][r] + __bfloat162float(bb[r]);
        if ((sign_[r] ^ sigm_[c]) & g) val -= 100.0f;
        s[c][r] = val;
        rmax[r] = fmaxf(rmax[r], val);
      }
    }
#pragma unroll
    for (int r = 0; r < 4; r++)
      for (int mm = 1; mm < 16; mm <<= 1) rmax[r] = fmaxf(rmax[r], __shfl_xor(rmax[r], mm));
    float rsum[4] = {0.f, 0.f, 0.f, 0.f};
#pragma unroll
    for (int c = 0; c < 9; c++)
#pragma unroll
      for (int r = 0; r < 4; r++) {
        float p = __expf(s[c][r] - rmax[r]);
        s[c][r] = p; rsum[r] += p;
      }
#pragma unroll
    for (int r = 0; r < 4; r++)
      for (int mm = 1; mm < 16; mm <<= 1) rsum[r] += __shfl_xor(rsum[r], mm);

    // V(wi+1) -> vT[cur^1] (safe: its last readers ran in window wi-1)
    if (wi < 7) {
      __hip_bfloat16 tmp[8]; *(uint4*)tmp = vreg;
      int tk = tid >> 2, c = tid & 3;
#pragma unroll
      for (int j = 0; j < 8; j++) vT[cur ^ 1][(c * 8 + j) * 168 + tk] = tmp[j];
    }

    // PV in 5 chunks of k=32: write P chunk (wave-private), read pa, 2 MFMA.
    floatx4 oacc[2] = {z4, z4};
#pragma unroll
    for (int t = 0; t < 5; t++) {
      if (t < 4) {
#pragma unroll
        for (int h2 = 0; h2 < 2; h2++) {
          int c = 2 * t + h2;
#pragma unroll
          for (int r = 0; r < 4; r++)
            pw[(lr4 + r) * 40 + h2 * 16 + lc] = __float2bfloat16(s[c][r]);
        }
      } else {
#pragma unroll
        for (int r = 0; r < 4; r++) {
          pw[(lr4 + r) * 40 + lc] = __float2bfloat16(s[8][r]);
          pw[(lr4 + r) * 40 + 16 + lc] = zb;
        }
      }
      short8 pa = *(short8*)(&pw[lc * 40 + lr * 8]);
      __builtin_amdgcn_s_setprio(1);
#pragma unroll
      for (int vt = 0; vt < 2; vt++) {
        short8 vbf = *(short8*)(&vT[cur][(vt * 16 + lc) * 168 + t * 32 + lr * 8]);
        oacc[vt] = __builtin_amdgcn_mfma_f32_16x16x32_bf16(pa, vbf, oacc[vt], 0, 0, 0);
      }
      __builtin_amdgcn_s_setprio(0);
    }
    float inv[4];
#pragma unroll
    for (int r = 0; r < 4; r++) inv[r] = 1.0f / rsum[r];
#pragma unroll
    for (int vt = 0; vt < 2; vt++)
#pragma unroll
      for (int r = 0; r < 4; r++)
        o[base + (rt * 16 + lr4 + r) * 32 + vt * 16 + lc] =
            __float2bfloat16(oacc[vt][r] * inv[r]);

    bar_lg();                             // publish vT[cur^1]; sync window
    cur ^= 1;
  }
}

// ---------------- host orchestration ----------------------------------------
extern "C" void kernel_launch(void* const* d_in, const int* in_sizes, int n_in,
                              void* d_out, int out_size, void* d_ws, size_t ws_size,
                              hipStream_t stream)
{
  const float* x_in  = (const float*)d_in[0];
  const float* n1w   = (const float*)d_in[1];
  const float* n1b   = (const float*)d_in[2];
  const float* qkvw  = (const float*)d_in[3];
  const float* qkvb  = (const float*)d_in[4];
  const float* btab  = (const float*)d_in[5];
  const float* projw = (const float*)d_in[6];
  const float* projb = (const float*)d_in[7];
  const float* n2w   = (const float*)d_in[8];
  const float* n2b   = (const float*)d_in[9];
  const float* w1    = (const float*)d_in[10];
  const float* b1    = (const float*)d_in[11];
  const float* w2    = (const float*)d_in[12];
  const float* b2    = (const float*)d_in[13];

  char* ws = (char*)d_ws;
  float* x            = (float*)(ws);                          // 113,246,208 B
  __hip_bfloat16* qb  = (__hip_bfloat16*)(ws + 169869312);     // q,k,v,o head-major
  __hip_bfloat16* kb  = qb + 28311552;
  __hip_bfloat16* vb  = kb + 28311552;
  __hip_bfloat16* ob  = vb + 28311552;
  __hip_bfloat16* Tb  = qb;                                    // MLP intermediate reuses region
  __hip_bfloat16* biasb = (__hip_bfloat16*)(ws + 396361728);
  __hip_bfloat16* wqkvT  = (__hip_bfloat16*)(ws + 428212224);
  __hip_bfloat16* wprojT = wqkvT + 110592;
  __hip_bfloat16* w1T    = wprojT + 36864;
  __hip_bfloat16* w2T    = w1T + 147456;

  for (int layer = 0; layer < 2; layer++) {
    int sz = layer ? 1 : 0, sh = layer ? 3 : 0, sw = layer ? 6 : 0;
    int masked = layer;
    const float* xsrc = (layer == 0) ? x_in : x;   // residual source

    convT4_kernel<<<1728, 256, 0, stream>>>(
        qkvw + (long)layer * 110592, projw + (long)layer * 36864,
        w1 + (long)layer * 147456, w2 + (long)layer * 147456,
        wqkvT, wprojT, w1T, w2T);
    biaspre_kernel<<<dim3(384, 9), 256, 0, stream>>>(btab + (long)layer * 3312 * 384, biasb);

    qkv_kernel<<<1152, 512, 0, stream>>>(
        xsrc, n1w + layer * 192, n1b + layer * 192, wqkvT, qkvb + layer * 576,
        qb, kb, vb, sz, sh, sw);
    attn_kernel<<<768, 576, 0, stream>>>(qb, kb, vb, biasb, ob, masked);
    proj_kernel<<<dim3(1152, 3), 256, 0, stream>>>(
        ob, wprojT, projb + layer * 192, xsrc, x, sz, sh, sw);
    mlp1_kernel<<<2304, 256, 0, stream>>>(
        x, n2w + layer * 192, n2b + layer * 192, w1T, b1 + layer * 768, Tb);
    mlp2_kernel<<<2304, 256, 0, stream>>>(
        Tb, w2T, b2 + layer * 192, x, (layer == 0) ? x : (float*)d_out);
  }
}